// Round 13
// baseline (119.039 us; speedup 1.0000x reference)
//
#include <hip/hip_runtime.h>
#include <math.h>

#define NN 100000
#define NE 1600000
#define FI 128
#define FH 64
#define FO 16
#define NB 392            // buckets of 256 nodes
#define BCAP 5632
#define AEPT 16
#define ACHUNK (256 * AEPT)                 // 4096 edges per phase-A block
#define ABLK ((NE + ACHUNK - 1) / ACHUNK)   // 391
#define GBLK ((NN + 63) / 64)               // 1563 gemm1 blocks

typedef unsigned short ushort_t;
typedef __attribute__((ext_vector_type(8))) short bf16x8;
typedef __attribute__((ext_vector_type(4))) float f32x4;

__device__ __forceinline__ ushort_t f2bf(float f) {
    unsigned u = __float_as_uint(f);
    u = (u + 0x7fffu + ((u >> 16) & 1u)) >> 16;  // RNE
    return (ushort_t)u;
}
__device__ __forceinline__ float bf_lo(unsigned u) {
    return __uint_as_float(u << 16);
}
__device__ __forceinline__ float bf_hi(unsigned u) {
    return __uint_as_float(u & 0xffff0000u);
}

__device__ __forceinline__ int load_dst(const int* edges, int mode, int e) {
    return mode ? edges[2 * (NE + e)] : edges[NE + e];
}
__device__ __forceinline__ int load_src(const int* edges, int mode, int e) {
    return mode ? edges[2 * e] : edges[e];
}

// ---- fused: blocks [0,ABLK) = phaseA edge sort; blocks [ABLK,..) = gemm1 MFMA ----
__global__ __launch_bounds__(256) void k_fuseA(const int* __restrict__ edges,
                                               unsigned* __restrict__ bcur,
                                               unsigned* __restrict__ staged,
                                               const float* __restrict__ x,
                                               const float* __restrict__ W1,
                                               ushort_t* __restrict__ h1p) {
    __shared__ unsigned pay_lds[ACHUNK];       // 16 KB
    __shared__ ushort_t bkt_lds[ACHUNK];       // 8 KB
    __shared__ unsigned hcnt[NB], hb[NB], dlt[NB], hcur[NB];
    __shared__ unsigned sc[512];
    __shared__ int smode;

    if (blockIdx.x >= ABLK) {
        // ================= gemm1: MFMA bf16 16x16x32, no LDS =================
        const int tid = threadIdx.x;
        const int l = tid & 63;
        const int w = tid >> 6;
        const int m = l & 15;
        const int g = l >> 4;
        const int node0 = (blockIdx.x - ABLK) * 64 + w * 16;

        bf16x8 bfrag[4][4];
#pragma unroll
        for (int ks = 0; ks < 4; ++ks)
#pragma unroll
            for (int nt = 0; nt < 4; ++nt)
#pragma unroll
                for (int e = 0; e < 8; ++e)
                    bfrag[ks][nt][e] = (short)f2bf(W1[(ks * 32 + g * 8 + e) * FH + nt * 16 + m]);

        f32x4 acc[4];
#pragma unroll
        for (int nt = 0; nt < 4; ++nt) acc[nt] = (f32x4){0.f, 0.f, 0.f, 0.f};

        int node = node0 + m;
        const float* xrow = x + (size_t)(node < NN ? node : NN - 1) * FI;
#pragma unroll
        for (int ks = 0; ks < 4; ++ks) {
            float4 xa = *(const float4*)&xrow[ks * 32 + g * 8];
            float4 xb = *(const float4*)&xrow[ks * 32 + g * 8 + 4];
            bf16x8 afrag;
            afrag[0] = (short)f2bf(xa.x);
            afrag[1] = (short)f2bf(xa.y);
            afrag[2] = (short)f2bf(xa.z);
            afrag[3] = (short)f2bf(xa.w);
            afrag[4] = (short)f2bf(xb.x);
            afrag[5] = (short)f2bf(xb.y);
            afrag[6] = (short)f2bf(xb.z);
            afrag[7] = (short)f2bf(xb.w);
#pragma unroll
            for (int nt = 0; nt < 4; ++nt)
                acc[nt] = __builtin_amdgcn_mfma_f32_16x16x32_bf16(afrag, bfrag[ks][nt], acc[nt], 0, 0, 0);
        }
#pragma unroll
        for (int nt = 0; nt < 4; ++nt)
#pragma unroll
            for (int r = 0; r < 4; ++r) {
                int outnode = node0 + g * 4 + r;
                if (outnode < NN)
                    h1p[(size_t)outnode * FH + nt * 16 + m] = f2bf(acc[nt][r]);
            }
        return;
    }

    // ================= phaseA: LDS counting sort, coalesced flush =================
    const int t = threadIdx.x;
    if (t == 0) {
        unsigned orv = 0;
        for (int i = 0; i < 16; ++i) orv |= (unsigned)edges[2 * i + 1];
        smode = (orv == 0u) ? 1 : 0;  // 1 = int64
    }
    for (int i = t; i < NB; i += 256) { hcnt[i] = 0; hcur[i] = 0; }
    __syncthreads();
    const int m = smode;
    const int base_e = blockIdx.x * ACHUNK;
    const int total = min(ACHUNK, NE - base_e);

    unsigned pay[AEPT];
    ushort_t bk[AEPT];
#pragma unroll
    for (int q = 0; q < AEPT; ++q) {
        int e = base_e + t + q * 256;
        pay[q] = 0;
        bk[q] = 0xffff;
        if (e < NE) {
            int d = load_dst(edges, m, e);
            int s = load_src(edges, m, e);
            pay[q] = ((unsigned)s << 8) | (unsigned)(d & 255);
            bk[q] = (ushort_t)(d >> 8);
            atomicAdd(&hcnt[d >> 8], 1u);
        }
    }
    __syncthreads();

    for (int i = t; i < NB; i += 256) dlt[i] = atomicAdd(&bcur[i], hcnt[i]);  // hrun
    sc[t] = (t < NB) ? hcnt[t] : 0u;
    sc[t + 256] = (t + 256 < NB) ? hcnt[t + 256] : 0u;
    __syncthreads();
    for (int ofs = 1; ofs < 512; ofs <<= 1) {
        unsigned v0 = (t >= ofs) ? sc[t - ofs] : 0u;
        unsigned v1 = (t + 256 >= ofs) ? sc[t + 256 - ofs] : 0u;
        __syncthreads();
        sc[t] += v0;
        sc[t + 256] += v1;
        __syncthreads();
    }
    for (int i = t; i < NB; i += 256) hb[i] = sc[i] - hcnt[i];
    __syncthreads();
    for (int i = t; i < NB; i += 256) dlt[i] = dlt[i] - hb[i];
    __syncthreads();

#pragma unroll
    for (int q = 0; q < AEPT; ++q) {
        if (bk[q] != 0xffff) {
            unsigned b = bk[q];
            unsigned r = atomicAdd(&hcur[b], 1u);
            unsigned idx = hb[b] + r;
            pay_lds[idx] = pay[q];
            bkt_lds[idx] = (ushort_t)b;
        }
    }
    __syncthreads();

    for (int i = t; i < total; i += 256) {
        unsigned b = bkt_lds[i];
        unsigned within = (unsigned)i + dlt[b];
        if (within < BCAP)
            staged[(size_t)b * BCAP + within] = pay_lds[i];
    }
}

// ---- phase B: bucket-base scan + per-bucket sort + dinv + h1p pre-scale ----
__global__ __launch_bounds__(256) void k_phaseB(const unsigned* __restrict__ staged,
                                                const unsigned* __restrict__ bcur,
                                                unsigned* __restrict__ rowstart,
                                                int* __restrict__ esrc,
                                                float* __restrict__ dinv,
                                                ushort_t* __restrict__ h1p) {
    __shared__ unsigned hist[256], hb[256], hcur[256], tmp[256];
    __shared__ unsigned sbc[512];
    const int b = blockIdx.x;
    const int t = threadIdx.x;

    // in-block scan of bcur -> this bucket's base
    sbc[t] = (t < NB) ? bcur[t] : 0u;
    sbc[t + 256] = (t + 256 < NB) ? bcur[t + 256] : 0u;
    __syncthreads();
    for (int ofs = 1; ofs < 512; ofs <<= 1) {
        unsigned v0 = (t >= ofs) ? sbc[t - ofs] : 0u;
        unsigned v1 = (t + 256 >= ofs) ? sbc[t + 256 - ofs] : 0u;
        __syncthreads();
        sbc[t] += v0;
        sbc[t + 256] += v1;
        __syncthreads();
    }
    const unsigned base = (b == 0) ? 0u : sbc[b - 1];
    const unsigned cnt = min(bcur[b], (unsigned)BCAP);

    hist[t] = 0;
    hcur[t] = 0;
    __syncthreads();
    const unsigned* sb = staged + (size_t)b * BCAP;
    for (unsigned i = t; i < cnt; i += 256) atomicAdd(&hist[sb[i] & 255u], 1u);
    __syncthreads();
    unsigned x = hist[t];
    tmp[t] = x;
    __syncthreads();
    for (int ofs = 1; ofs < 256; ofs <<= 1) {
        unsigned v = (t >= ofs) ? tmp[t - ofs] : 0u;
        __syncthreads();
        tmp[t] += v;
        __syncthreads();
    }
    hb[t] = tmp[t] - x;
    int v = b * 256 + t;
    float dv = rsqrtf((float)(1u + x));
    if (v <= NN) rowstart[v] = base + hb[t];
    if (v < NN) dinv[v] = dv;
    __syncthreads();
    for (unsigned i = t; i < cnt; i += 256) {
        unsigned p = sb[i];
        unsigned dlo = p & 255u;
        unsigned pos = base + hb[dlo] + atomicAdd(&hcur[dlo], 1u);
        esrc[pos] = (int)(p >> 8);
    }

    // ---- pre-scale h1p rows of this block's 256 nodes by their dinv ----
    __syncthreads();
    tmp[t] = __float_as_uint(dv);   // tmp now free; share dinv across waves
    __syncthreads();
    unsigned* h32 = (unsigned*)h1p;
    const int w = t >> 6;
    const int lane = t & 63;
    const int half = lane >> 5;     // 2 rows per iteration per wave
    const int ui = lane & 31;       // uint within 128B row
#pragma unroll 4
    for (int r2 = 0; r2 < 32; ++r2) {
        int local = w * 64 + r2 * 2 + half;
        int node = b * 256 + local;
        if (node < NN) {
            float dvr = __uint_as_float(tmp[local]);
            size_t idx = (size_t)node * 32 + ui;
            unsigned u = h32[idx];
            float lo = bf_lo(u) * dvr;
            float hi = bf_hi(u) * dvr;
            h32[idx] = (unsigned)f2bf(lo) | ((unsigned)f2bf(hi) << 16);
        }
    }
}

// ---- fused layer1 aggregate + GEMM2 (rows prescaled: per-edge = load+add) ----
__global__ __launch_bounds__(256) void k_gather1f(const unsigned* __restrict__ rowstart,
                                                  const int* __restrict__ esrc,
                                                  const ushort_t* __restrict__ h1p,
                                                  const float* __restrict__ dinv,
                                                  const float* __restrict__ b1,
                                                  const float* __restrict__ W2,
                                                  ushort_t* __restrict__ h2p) {
    __shared__ float Ws2t[FO][FH];  // Ws2t[j][k] = W2[k][j]
    {
        int t = threadIdx.x;
#pragma unroll
        for (int i = 0; i < 4; ++i) {
            int q = t * 4 + i;
            int k = q >> 4, j = q & 15;
            Ws2t[j][k] = W2[q];
        }
    }
    __syncthreads();

    int wave = (blockIdx.x * 256 + threadIdx.x) >> 6;
    int lane = threadIdx.x & 63;
    int grp = lane >> 4;
    int fj = lane & 15;
    int v = wave * 4 + grp;
    if (v >= NN) return;

    const uint2* h2v = (const uint2*)h1p;
    unsigned beg = rowstart[v], end = rowstart[v + 1];
    float dv = dinv[v];
    float a0 = 0.f, a1 = 0.f, a2 = 0.f, a3 = 0.f;
    unsigned i = beg;
    int ns0 = 0, ns1 = 0, ns2 = 0, ns3 = 0;
    if (i + 3 < end) { ns0 = esrc[i]; ns1 = esrc[i + 1]; ns2 = esrc[i + 2]; ns3 = esrc[i + 3]; }
    while (i + 3 < end) {
        int s0 = ns0, s1 = ns1, s2 = ns2, s3 = ns3;
        unsigned nx = i + 4;
        if (nx + 3 < end) { ns0 = esrc[nx]; ns1 = esrc[nx + 1]; ns2 = esrc[nx + 2]; ns3 = esrc[nx + 3]; }
        uint2 u0 = h2v[(size_t)s0 * 16 + fj];
        uint2 u1 = h2v[(size_t)s1 * 16 + fj];
        uint2 u2 = h2v[(size_t)s2 * 16 + fj];
        uint2 u3 = h2v[(size_t)s3 * 16 + fj];
        a0 += (bf_lo(u0.x) + bf_lo(u1.x)) + (bf_lo(u2.x) + bf_lo(u3.x));
        a1 += (bf_hi(u0.x) + bf_hi(u1.x)) + (bf_hi(u2.x) + bf_hi(u3.x));
        a2 += (bf_lo(u0.y) + bf_lo(u1.y)) + (bf_lo(u2.y) + bf_lo(u3.y));
        a3 += (bf_hi(u0.y) + bf_hi(u1.y)) + (bf_hi(u2.y) + bf_hi(u3.y));
        i = nx;
    }
    for (; i < end; ++i) {
        int s = esrc[i];
        uint2 u = h2v[(size_t)s * 16 + fj];
        a0 += bf_lo(u.x);
        a1 += bf_hi(u.x);
        a2 += bf_lo(u.y);
        a3 += bf_hi(u.y);
    }
    // layer1 finish: val = (acc + self') * dv + b1 ; relu
    uint2 us = h2v[(size_t)v * 16 + fj];
    float4 bb = ((const float4*)b1)[fj];
    float r0 = fmaxf(fmaf(a0 + bf_lo(us.x), dv, bb.x), 0.f);
    float r1 = fmaxf(fmaf(a1 + bf_hi(us.x), dv, bb.y), 0.f);
    float r2 = fmaxf(fmaf(a2 + bf_lo(us.y), dv, bb.z), 0.f);
    float r3 = fmaxf(fmaf(a3 + bf_hi(us.y), dv, bb.w), 0.f);

    float p[16];
#pragma unroll
    for (int j = 0; j < 16; ++j) {
        float4 w = *(const float4*)&Ws2t[j][fj * 4];
        p[j] = r0 * w.x + r1 * w.y + r2 * w.z + r3 * w.w;
    }
    bool c0 = (fj & 1) != 0;
    float q8[8];
#pragma unroll
    for (int k = 0; k < 8; ++k) {
        float sent = c0 ? p[2 * k] : p[2 * k + 1];
        float kept = c0 ? p[2 * k + 1] : p[2 * k];
        q8[k] = kept + __shfl_xor(sent, 1);
    }
    bool c1 = (fj & 2) != 0;
    float q4[4];
#pragma unroll
    for (int k = 0; k < 4; ++k) {
        float sent = c1 ? q8[2 * k] : q8[2 * k + 1];
        float kept = c1 ? q8[2 * k + 1] : q8[2 * k];
        q4[k] = kept + __shfl_xor(sent, 2);
    }
    bool c2 = (fj & 4) != 0;
    float q2[2];
#pragma unroll
    for (int k = 0; k < 2; ++k) {
        float sent = c2 ? q4[2 * k] : q4[2 * k + 1];
        float kept = c2 ? q4[2 * k + 1] : q4[2 * k];
        q2[k] = kept + __shfl_xor(sent, 4);
    }
    bool c3 = (fj & 8) != 0;
    {
        float sent = c3 ? q2[0] : q2[1];
        float kept = c3 ? q2[1] : q2[0];
        float fin = kept + __shfl_xor(sent, 8);
        // store h2p' = h2p * dinv[v]  (prescaled for gather2)
        h2p[(size_t)v * FO + fj] = f2bf(fin * dv);
    }
}

// ---- layer2 aggregate (rows prescaled) + bias + log_softmax ----
__global__ __launch_bounds__(256) void k_gather2(const unsigned* __restrict__ rowstart,
                                                 const int* __restrict__ esrc,
                                                 const ushort_t* __restrict__ h2p,
                                                 const float* __restrict__ dinv,
                                                 const float* __restrict__ b,
                                                 float* __restrict__ out) {
    int wave = (blockIdx.x * 256 + threadIdx.x) >> 6;
    int lane = threadIdx.x & 63;
    int grp = lane >> 4;
    int j = lane & 15;
    int v = wave * 4 + grp;
    if (v >= NN) return;
    unsigned beg = rowstart[v], end = rowstart[v + 1];
    float dv = dinv[v];
    float acc = 0.f;
    unsigned i = beg;
    int ns0 = 0, ns1 = 0, ns2 = 0, ns3 = 0;
    if (i + 3 < end) { ns0 = esrc[i]; ns1 = esrc[i + 1]; ns2 = esrc[i + 2]; ns3 = esrc[i + 3]; }
    while (i + 3 < end) {
        int s0 = ns0, s1 = ns1, s2 = ns2, s3 = ns3;
        unsigned nx = i + 4;
        if (nx + 3 < end) { ns0 = esrc[nx]; ns1 = esrc[nx + 1]; ns2 = esrc[nx + 2]; ns3 = esrc[nx + 3]; }
        float x0 = __uint_as_float((unsigned)h2p[(size_t)s0 * FO + j] << 16);
        float x1 = __uint_as_float((unsigned)h2p[(size_t)s1 * FO + j] << 16);
        float x2 = __uint_as_float((unsigned)h2p[(size_t)s2 * FO + j] << 16);
        float x3 = __uint_as_float((unsigned)h2p[(size_t)s3 * FO + j] << 16);
        acc += (x0 + x1) + (x2 + x3);
        i = nx;
    }
    for (; i < end; ++i) {
        int s = esrc[i];
        acc += __uint_as_float((unsigned)h2p[(size_t)s * FO + j] << 16);
    }
    float self = __uint_as_float((unsigned)h2p[(size_t)v * FO + j] << 16);
    float val = fmaf(acc + self, dv, b[j]);
    float m = val;
#pragma unroll
    for (int w = 1; w < 16; w <<= 1) m = fmaxf(m, __shfl_xor(m, w));
    float ex = expf(val - m);
    float ssum = ex;
#pragma unroll
    for (int w = 1; w < 16; w <<= 1) ssum += __shfl_xor(ssum, w);
    float res = val - (m + logf(ssum));
    out[(size_t)v * FO + j] = res;
}

extern "C" void kernel_launch(void* const* d_in, const int* in_sizes, int n_in,
                              void* d_out, int out_size, void* d_ws, size_t ws_size,
                              hipStream_t stream) {
    const float* x = (const float*)d_in[0];
    const int* edges = (const int*)d_in[1];
    const float* W1 = (const float*)d_in[2];
    const float* b1 = (const float*)d_in[3];
    const float* W2 = (const float*)d_in[4];
    const float* b2 = (const float*)d_in[5];
    float* out = (float*)d_out;

    char* ws = (char*)d_ws;
    size_t off = 0;
    auto take = [&](size_t bytes) {
        void* p = ws + off;
        off += (bytes + 255) & ~(size_t)255;
        return p;
    };
    unsigned* bcur = (unsigned*)take((size_t)NB * 4);
    unsigned* rowstart = (unsigned*)take((size_t)(NN + 1) * 4);
    float* dinv = (float*)take((size_t)NN * 4);
    int* esrc = (int*)take((size_t)NE * 4);
    ushort_t* h1p = (ushort_t*)take((size_t)NN * FH * 2);   // bf16, prescaled by phaseB
    ushort_t* h2p = (ushort_t*)take((size_t)NN * FO * 2);   // bf16, prescaled
    unsigned* staged = (unsigned*)take((size_t)NB * BCAP * 4);  // 8.8 MB

    hipMemsetAsync(bcur, 0, (size_t)NB * 4, stream);
    k_fuseA<<<ABLK + GBLK, 256, 0, stream>>>(edges, bcur, staged, x, W1, h1p);
    k_phaseB<<<NB, 256, 0, stream>>>(staged, bcur, rowstart, esrc, dinv, h1p);
    k_gather1f<<<(NN + 15) / 16, 256, 0, stream>>>(rowstart, esrc, h1p, dinv, b1, W2, h2p);
    k_gather2<<<(NN + 15) / 16, 256, 0, stream>>>(rowstart, esrc, h2p, dinv, b2, out);
}

// Round 14
// 110.694 us; speedup vs baseline: 1.0754x; 1.0754x over previous
//
#include <hip/hip_runtime.h>
#include <math.h>

#define NN 100000
#define NE 1600000
#define FI 128
#define FH 64
#define FO 16
#define NB 392            // buckets of 256 nodes
#define BCAP 5632
#define AEPT 16
#define ACHUNK (256 * AEPT)                 // 4096 edges per phase-A block
#define ABLK ((NE + ACHUNK - 1) / ACHUNK)   // 391
#define GBLK ((NN + 63) / 64)               // 1563 gemm1 blocks

typedef unsigned short ushort_t;
typedef __attribute__((ext_vector_type(8))) short bf16x8;
typedef __attribute__((ext_vector_type(4))) float f32x4;

__device__ __forceinline__ ushort_t f2bf(float f) {
    unsigned u = __float_as_uint(f);
    u = (u + 0x7fffu + ((u >> 16) & 1u)) >> 16;  // RNE
    return (ushort_t)u;
}
__device__ __forceinline__ float bf_lo(unsigned u) {
    return __uint_as_float(u << 16);
}
__device__ __forceinline__ float bf_hi(unsigned u) {
    return __uint_as_float(u & 0xffff0000u);
}

__device__ __forceinline__ int load_dst(const int* edges, int mode, int e) {
    return mode ? edges[2 * (NE + e)] : edges[NE + e];
}
__device__ __forceinline__ int load_src(const int* edges, int mode, int e) {
    return mode ? edges[2 * e] : edges[e];
}

// ---- fused: blocks [0,ABLK) = phaseA edge sort; blocks [ABLK,..) = gemm1 MFMA ----
__global__ __launch_bounds__(256) void k_fuseA(const int* __restrict__ edges,
                                               unsigned* __restrict__ bcur,
                                               unsigned* __restrict__ staged,
                                               const float* __restrict__ x,
                                               const float* __restrict__ W1,
                                               ushort_t* __restrict__ h1p) {
    __shared__ unsigned pay_lds[ACHUNK];       // 16 KB
    __shared__ ushort_t bkt_lds[ACHUNK];       // 8 KB
    __shared__ unsigned hcnt[NB], hb[NB], dlt[NB], hcur[NB];
    __shared__ unsigned sc[512];
    __shared__ int smode;

    if (blockIdx.x >= ABLK) {
        // ================= gemm1: MFMA bf16 16x16x32, no LDS =================
        const int tid = threadIdx.x;
        const int l = tid & 63;
        const int w = tid >> 6;
        const int m = l & 15;
        const int g = l >> 4;
        const int node0 = (blockIdx.x - ABLK) * 64 + w * 16;

        bf16x8 bfrag[4][4];
#pragma unroll
        for (int ks = 0; ks < 4; ++ks)
#pragma unroll
            for (int nt = 0; nt < 4; ++nt)
#pragma unroll
                for (int e = 0; e < 8; ++e)
                    bfrag[ks][nt][e] = (short)f2bf(W1[(ks * 32 + g * 8 + e) * FH + nt * 16 + m]);

        f32x4 acc[4];
#pragma unroll
        for (int nt = 0; nt < 4; ++nt) acc[nt] = (f32x4){0.f, 0.f, 0.f, 0.f};

        int node = node0 + m;
        const float* xrow = x + (size_t)(node < NN ? node : NN - 1) * FI;
#pragma unroll
        for (int ks = 0; ks < 4; ++ks) {
            float4 xa = *(const float4*)&xrow[ks * 32 + g * 8];
            float4 xb = *(const float4*)&xrow[ks * 32 + g * 8 + 4];
            bf16x8 afrag;
            afrag[0] = (short)f2bf(xa.x);
            afrag[1] = (short)f2bf(xa.y);
            afrag[2] = (short)f2bf(xa.z);
            afrag[3] = (short)f2bf(xa.w);
            afrag[4] = (short)f2bf(xb.x);
            afrag[5] = (short)f2bf(xb.y);
            afrag[6] = (short)f2bf(xb.z);
            afrag[7] = (short)f2bf(xb.w);
#pragma unroll
            for (int nt = 0; nt < 4; ++nt)
                acc[nt] = __builtin_amdgcn_mfma_f32_16x16x32_bf16(afrag, bfrag[ks][nt], acc[nt], 0, 0, 0);
        }
#pragma unroll
        for (int nt = 0; nt < 4; ++nt)
#pragma unroll
            for (int r = 0; r < 4; ++r) {
                int outnode = node0 + g * 4 + r;
                if (outnode < NN)
                    h1p[(size_t)outnode * FH + nt * 16 + m] = f2bf(acc[nt][r]);
            }
        return;
    }

    // ================= phaseA: LDS counting sort, coalesced flush =================
    const int t = threadIdx.x;
    if (t == 0) {
        unsigned orv = 0;
        for (int i = 0; i < 16; ++i) orv |= (unsigned)edges[2 * i + 1];
        smode = (orv == 0u) ? 1 : 0;  // 1 = int64
    }
    for (int i = t; i < NB; i += 256) { hcnt[i] = 0; hcur[i] = 0; }
    __syncthreads();
    const int m = smode;
    const int base_e = blockIdx.x * ACHUNK;
    const int total = min(ACHUNK, NE - base_e);

    unsigned pay[AEPT];
    ushort_t bk[AEPT];
#pragma unroll
    for (int q = 0; q < AEPT; ++q) {
        int e = base_e + t + q * 256;
        pay[q] = 0;
        bk[q] = 0xffff;
        if (e < NE) {
            int d = load_dst(edges, m, e);
            int s = load_src(edges, m, e);
            pay[q] = ((unsigned)s << 8) | (unsigned)(d & 255);
            bk[q] = (ushort_t)(d >> 8);
            atomicAdd(&hcnt[d >> 8], 1u);
        }
    }
    __syncthreads();

    for (int i = t; i < NB; i += 256) dlt[i] = atomicAdd(&bcur[i], hcnt[i]);  // hrun
    sc[t] = (t < NB) ? hcnt[t] : 0u;
    sc[t + 256] = (t + 256 < NB) ? hcnt[t + 256] : 0u;
    __syncthreads();
    for (int ofs = 1; ofs < 512; ofs <<= 1) {
        unsigned v0 = (t >= ofs) ? sc[t - ofs] : 0u;
        unsigned v1 = (t + 256 >= ofs) ? sc[t + 256 - ofs] : 0u;
        __syncthreads();
        sc[t] += v0;
        sc[t + 256] += v1;
        __syncthreads();
    }
    for (int i = t; i < NB; i += 256) hb[i] = sc[i] - hcnt[i];
    __syncthreads();
    for (int i = t; i < NB; i += 256) dlt[i] = dlt[i] - hb[i];
    __syncthreads();

#pragma unroll
    for (int q = 0; q < AEPT; ++q) {
        if (bk[q] != 0xffff) {
            unsigned b = bk[q];
            unsigned r = atomicAdd(&hcur[b], 1u);
            unsigned idx = hb[b] + r;
            pay_lds[idx] = pay[q];
            bkt_lds[idx] = (ushort_t)b;
        }
    }
    __syncthreads();

    for (int i = t; i < total; i += 256) {
        unsigned b = bkt_lds[i];
        unsigned within = (unsigned)i + dlt[b];
        if (within < BCAP)
            staged[(size_t)b * BCAP + within] = pay_lds[i];
    }
}

// ---- phase B: bucket-base scan + per-bucket counting sort + dinv ----
__global__ __launch_bounds__(256) void k_phaseB(const unsigned* __restrict__ staged,
                                                const unsigned* __restrict__ bcur,
                                                unsigned* __restrict__ rowstart,
                                                int* __restrict__ esrc,
                                                float* __restrict__ dinv) {
    __shared__ unsigned hist[256], hb[256], hcur[256], tmp[256];
    __shared__ unsigned sbc[512];
    const int b = blockIdx.x;
    const int t = threadIdx.x;

    sbc[t] = (t < NB) ? bcur[t] : 0u;
    sbc[t + 256] = (t + 256 < NB) ? bcur[t + 256] : 0u;
    __syncthreads();
    for (int ofs = 1; ofs < 512; ofs <<= 1) {
        unsigned v0 = (t >= ofs) ? sbc[t - ofs] : 0u;
        unsigned v1 = (t + 256 >= ofs) ? sbc[t + 256 - ofs] : 0u;
        __syncthreads();
        sbc[t] += v0;
        sbc[t + 256] += v1;
        __syncthreads();
    }
    const unsigned base = (b == 0) ? 0u : sbc[b - 1];
    const unsigned cnt = min(bcur[b], (unsigned)BCAP);

    hist[t] = 0;
    hcur[t] = 0;
    __syncthreads();
    const unsigned* sb = staged + (size_t)b * BCAP;
    for (unsigned i = t; i < cnt; i += 256) atomicAdd(&hist[sb[i] & 255u], 1u);
    __syncthreads();
    unsigned x = hist[t];
    tmp[t] = x;
    __syncthreads();
    for (int ofs = 1; ofs < 256; ofs <<= 1) {
        unsigned v = (t >= ofs) ? tmp[t - ofs] : 0u;
        __syncthreads();
        tmp[t] += v;
        __syncthreads();
    }
    hb[t] = tmp[t] - x;
    int v = b * 256 + t;
    if (v <= NN) rowstart[v] = base + hb[t];
    if (v < NN) dinv[v] = rsqrtf((float)(1u + x));
    __syncthreads();
    for (unsigned i = t; i < cnt; i += 256) {
        unsigned p = sb[i];
        unsigned dlo = p & 255u;
        unsigned pos = base + hb[dlo] + atomicAdd(&hcur[dlo], 1u);
        esrc[pos] = (int)(p >> 8);
    }
}

// ---- fused layer1 aggregate + GEMM2: 4 nodes/wave, 16 lanes/node, esrc prefetch ----
// epilogue stores h2p' = h2 * dinv[v]  (prescaled for gather2 — free here)
__global__ __launch_bounds__(256) void k_gather1f(const unsigned* __restrict__ rowstart,
                                                  const int* __restrict__ esrc,
                                                  const ushort_t* __restrict__ h1p,
                                                  const float* __restrict__ dinv,
                                                  const float* __restrict__ b1,
                                                  const float* __restrict__ W2,
                                                  ushort_t* __restrict__ h2p) {
    __shared__ float Ws2t[FO][FH];  // Ws2t[j][k] = W2[k][j]
    {
        int t = threadIdx.x;
#pragma unroll
        for (int i = 0; i < 4; ++i) {
            int q = t * 4 + i;
            int k = q >> 4, j = q & 15;
            Ws2t[j][k] = W2[q];
        }
    }
    __syncthreads();

    int wave = (blockIdx.x * 256 + threadIdx.x) >> 6;
    int lane = threadIdx.x & 63;
    int grp = lane >> 4;
    int fj = lane & 15;
    int v = wave * 4 + grp;
    if (v >= NN) return;

    const uint2* h2v = (const uint2*)h1p;
    unsigned beg = rowstart[v], end = rowstart[v + 1];
    float dv = dinv[v];
    float a0 = 0.f, a1 = 0.f, a2 = 0.f, a3 = 0.f;
    unsigned i = beg;
    int ns0 = 0, ns1 = 0, ns2 = 0, ns3 = 0;
    if (i + 3 < end) { ns0 = esrc[i]; ns1 = esrc[i + 1]; ns2 = esrc[i + 2]; ns3 = esrc[i + 3]; }
    while (i + 3 < end) {
        int s0 = ns0, s1 = ns1, s2 = ns2, s3 = ns3;
        unsigned nx = i + 4;
        if (nx + 3 < end) { ns0 = esrc[nx]; ns1 = esrc[nx + 1]; ns2 = esrc[nx + 2]; ns3 = esrc[nx + 3]; }
        float n0 = dinv[s0] * dv, n1 = dinv[s1] * dv;
        float n2 = dinv[s2] * dv, n3 = dinv[s3] * dv;
        uint2 u0 = h2v[(size_t)s0 * 16 + fj];
        uint2 u1 = h2v[(size_t)s1 * 16 + fj];
        uint2 u2 = h2v[(size_t)s2 * 16 + fj];
        uint2 u3 = h2v[(size_t)s3 * 16 + fj];
        a0 += bf_lo(u0.x) * n0 + bf_lo(u1.x) * n1 + bf_lo(u2.x) * n2 + bf_lo(u3.x) * n3;
        a1 += bf_hi(u0.x) * n0 + bf_hi(u1.x) * n1 + bf_hi(u2.x) * n2 + bf_hi(u3.x) * n3;
        a2 += bf_lo(u0.y) * n0 + bf_lo(u1.y) * n1 + bf_lo(u2.y) * n2 + bf_lo(u3.y) * n3;
        a3 += bf_hi(u0.y) * n0 + bf_hi(u1.y) * n1 + bf_hi(u2.y) * n2 + bf_hi(u3.y) * n3;
        i = nx;
    }
    for (; i < end; ++i) {
        int s = esrc[i];
        float n = dinv[s] * dv;
        uint2 u = h2v[(size_t)s * 16 + fj];
        a0 += bf_lo(u.x) * n;
        a1 += bf_hi(u.x) * n;
        a2 += bf_lo(u.y) * n;
        a3 += bf_hi(u.y) * n;
    }
    float di2 = dv * dv;
    uint2 us = h2v[(size_t)v * 16 + fj];
    float4 bb = ((const float4*)b1)[fj];
    float r0 = fmaxf(a0 + bf_lo(us.x) * di2 + bb.x, 0.f);
    float r1 = fmaxf(a1 + bf_hi(us.x) * di2 + bb.y, 0.f);
    float r2 = fmaxf(a2 + bf_lo(us.y) * di2 + bb.z, 0.f);
    float r3 = fmaxf(a3 + bf_hi(us.y) * di2 + bb.w, 0.f);

    float p[16];
#pragma unroll
    for (int j = 0; j < 16; ++j) {
        float4 w = *(const float4*)&Ws2t[j][fj * 4];
        p[j] = r0 * w.x + r1 * w.y + r2 * w.z + r3 * w.w;
    }
    bool c0 = (fj & 1) != 0;
    float q8[8];
#pragma unroll
    for (int k = 0; k < 8; ++k) {
        float sent = c0 ? p[2 * k] : p[2 * k + 1];
        float kept = c0 ? p[2 * k + 1] : p[2 * k];
        q8[k] = kept + __shfl_xor(sent, 1);
    }
    bool c1 = (fj & 2) != 0;
    float q4[4];
#pragma unroll
    for (int k = 0; k < 4; ++k) {
        float sent = c1 ? q8[2 * k] : q8[2 * k + 1];
        float kept = c1 ? q8[2 * k + 1] : q8[2 * k];
        q4[k] = kept + __shfl_xor(sent, 2);
    }
    bool c2 = (fj & 4) != 0;
    float q2[2];
#pragma unroll
    for (int k = 0; k < 2; ++k) {
        float sent = c2 ? q4[2 * k] : q4[2 * k + 1];
        float kept = c2 ? q4[2 * k + 1] : q4[2 * k];
        q2[k] = kept + __shfl_xor(sent, 4);
    }
    bool c3 = (fj & 8) != 0;
    {
        float sent = c3 ? q2[0] : q2[1];
        float kept = c3 ? q2[1] : q2[0];
        float fin = kept + __shfl_xor(sent, 8);
        h2p[(size_t)v * FO + fj] = f2bf(fin * dv);  // prescaled
    }
}

// ---- layer2 aggregate (rows prescaled) + bias + log_softmax ----
__global__ __launch_bounds__(256) void k_gather2(const unsigned* __restrict__ rowstart,
                                                 const int* __restrict__ esrc,
                                                 const ushort_t* __restrict__ h2p,
                                                 const float* __restrict__ dinv,
                                                 const float* __restrict__ b,
                                                 float* __restrict__ out) {
    int wave = (blockIdx.x * 256 + threadIdx.x) >> 6;
    int lane = threadIdx.x & 63;
    int grp = lane >> 4;
    int j = lane & 15;
    int v = wave * 4 + grp;
    if (v >= NN) return;
    unsigned beg = rowstart[v], end = rowstart[v + 1];
    float dv = dinv[v];
    float acc = 0.f;
    unsigned i = beg;
    int ns0 = 0, ns1 = 0, ns2 = 0, ns3 = 0;
    if (i + 3 < end) { ns0 = esrc[i]; ns1 = esrc[i + 1]; ns2 = esrc[i + 2]; ns3 = esrc[i + 3]; }
    while (i + 3 < end) {
        int s0 = ns0, s1 = ns1, s2 = ns2, s3 = ns3;
        unsigned nx = i + 4;
        if (nx + 3 < end) { ns0 = esrc[nx]; ns1 = esrc[nx + 1]; ns2 = esrc[nx + 2]; ns3 = esrc[nx + 3]; }
        float x0 = __uint_as_float((unsigned)h2p[(size_t)s0 * FO + j] << 16);
        float x1 = __uint_as_float((unsigned)h2p[(size_t)s1 * FO + j] << 16);
        float x2 = __uint_as_float((unsigned)h2p[(size_t)s2 * FO + j] << 16);
        float x3 = __uint_as_float((unsigned)h2p[(size_t)s3 * FO + j] << 16);
        acc += (x0 + x1) + (x2 + x3);
        i = nx;
    }
    for (; i < end; ++i) {
        int s = esrc[i];
        acc += __uint_as_float((unsigned)h2p[(size_t)s * FO + j] << 16);
    }
    float self = __uint_as_float((unsigned)h2p[(size_t)v * FO + j] << 16);
    float val = fmaf(acc + self, dv, b[j]);
    float m = val;
#pragma unroll
    for (int w = 1; w < 16; w <<= 1) m = fmaxf(m, __shfl_xor(m, w));
    float ex = expf(val - m);
    float ssum = ex;
#pragma unroll
    for (int w = 1; w < 16; w <<= 1) ssum += __shfl_xor(ssum, w);
    float res = val - (m + logf(ssum));
    out[(size_t)v * FO + j] = res;
}

extern "C" void kernel_launch(void* const* d_in, const int* in_sizes, int n_in,
                              void* d_out, int out_size, void* d_ws, size_t ws_size,
                              hipStream_t stream) {
    const float* x = (const float*)d_in[0];
    const int* edges = (const int*)d_in[1];
    const float* W1 = (const float*)d_in[2];
    const float* b1 = (const float*)d_in[3];
    const float* W2 = (const float*)d_in[4];
    const float* b2 = (const float*)d_in[5];
    float* out = (float*)d_out;

    char* ws = (char*)d_ws;
    size_t off = 0;
    auto take = [&](size_t bytes) {
        void* p = ws + off;
        off += (bytes + 255) & ~(size_t)255;
        return p;
    };
    unsigned* bcur = (unsigned*)take((size_t)NB * 4);
    unsigned* rowstart = (unsigned*)take((size_t)(NN + 1) * 4);
    float* dinv = (float*)take((size_t)NN * 4);
    int* esrc = (int*)take((size_t)NE * 4);
    ushort_t* h1p = (ushort_t*)take((size_t)NN * FH * 2);   // bf16
    ushort_t* h2p = (ushort_t*)take((size_t)NN * FO * 2);   // bf16, prescaled by gather1f
    unsigned* staged = (unsigned*)take((size_t)NB * BCAP * 4);  // 8.8 MB

    hipMemsetAsync(bcur, 0, (size_t)NB * 4, stream);
    k_fuseA<<<ABLK + GBLK, 256, 0, stream>>>(edges, bcur, staged, x, W1, h1p);
    k_phaseB<<<NB, 256, 0, stream>>>(staged, bcur, rowstart, esrc, dinv);
    k_gather1f<<<(NN + 15) / 16, 256, 0, stream>>>(rowstart, esrc, h1p, dinv, b1, W2, h2p);
    k_gather2<<<(NN + 15) / 16, 256, 0, stream>>>(rowstart, esrc, h2p, dinv, b2, out);
}

// Round 15
// 104.628 us; speedup vs baseline: 1.1377x; 1.0580x over previous
//
#include <hip/hip_runtime.h>
#include <math.h>

#define NN 100000
#define NE 1600000
#define FI 128
#define FH 64
#define FO 16
#define NB 392            // buckets of 256 nodes
#define BCAP 5632
#define AEPT 16
#define ACHUNK (256 * AEPT)                 // 4096 edges per phase-A block
#define ABLK ((NE + ACHUNK - 1) / ACHUNK)   // 391
#define GBLK ((NN + 63) / 64)               // 1563 gemm1 blocks

typedef unsigned short ushort_t;
typedef unsigned char uchar_t;
typedef __attribute__((ext_vector_type(8))) short bf16x8;
typedef __attribute__((ext_vector_type(4))) float f32x4;

__device__ __forceinline__ ushort_t f2bf(float f) {
    unsigned u = __float_as_uint(f);
    u = (u + 0x7fffu + ((u >> 16) & 1u)) >> 16;  // RNE
    return (ushort_t)u;
}
__device__ __forceinline__ float bf_lo(unsigned u) {
    return __uint_as_float(u << 16);
}
__device__ __forceinline__ float bf_hi(unsigned u) {
    return __uint_as_float(u & 0xffff0000u);
}

__device__ __forceinline__ int load_dst(const int* edges, int mode, int e) {
    return mode ? edges[2 * (NE + e)] : edges[NE + e];
}
__device__ __forceinline__ int load_src(const int* edges, int mode, int e) {
    return mode ? edges[2 * e] : edges[e];
}

// ---- fused: blocks [0,ABLK) = phaseA edge sort; blocks [ABLK,..) = gemm1 MFMA ----
__global__ __launch_bounds__(256) void k_fuseA(const int* __restrict__ edges,
                                               unsigned* __restrict__ bcur,
                                               unsigned* __restrict__ staged,
                                               const float* __restrict__ x,
                                               const float* __restrict__ W1,
                                               uchar_t* __restrict__ h1p) {
    __shared__ unsigned pay_lds[ACHUNK];       // 16 KB
    __shared__ ushort_t bkt_lds[ACHUNK];       // 8 KB
    __shared__ unsigned hcnt[NB], hb[NB], dlt[NB], hcur[NB];
    __shared__ unsigned sc[512];
    __shared__ int smode;

    if (blockIdx.x >= ABLK) {
        // ================= gemm1: MFMA bf16 16x16x32, fp8 output =================
        const int tid = threadIdx.x;
        const int l = tid & 63;
        const int w = tid >> 6;
        const int m = l & 15;
        const int g = l >> 4;
        const int node0 = (blockIdx.x - ABLK) * 64 + w * 16;

        bf16x8 bfrag[4][4];
#pragma unroll
        for (int ks = 0; ks < 4; ++ks)
#pragma unroll
            for (int nt = 0; nt < 4; ++nt)
#pragma unroll
                for (int e = 0; e < 8; ++e)
                    bfrag[ks][nt][e] = (short)f2bf(W1[(ks * 32 + g * 8 + e) * FH + nt * 16 + m]);

        f32x4 acc[4];
#pragma unroll
        for (int nt = 0; nt < 4; ++nt) acc[nt] = (f32x4){0.f, 0.f, 0.f, 0.f};

        int node = node0 + m;
        const float* xrow = x + (size_t)(node < NN ? node : NN - 1) * FI;
#pragma unroll
        for (int ks = 0; ks < 4; ++ks) {
            float4 xa = *(const float4*)&xrow[ks * 32 + g * 8];
            float4 xb = *(const float4*)&xrow[ks * 32 + g * 8 + 4];
            bf16x8 afrag;
            afrag[0] = (short)f2bf(xa.x);
            afrag[1] = (short)f2bf(xa.y);
            afrag[2] = (short)f2bf(xa.z);
            afrag[3] = (short)f2bf(xa.w);
            afrag[4] = (short)f2bf(xb.x);
            afrag[5] = (short)f2bf(xb.y);
            afrag[6] = (short)f2bf(xb.z);
            afrag[7] = (short)f2bf(xb.w);
#pragma unroll
            for (int nt = 0; nt < 4; ++nt)
                acc[nt] = __builtin_amdgcn_mfma_f32_16x16x32_bf16(afrag, bfrag[ks][nt], acc[nt], 0, 0, 0);
        }
#pragma unroll
        for (int nt = 0; nt < 4; ++nt)
#pragma unroll
            for (int r = 0; r < 4; ++r) {
                int outnode = node0 + g * 4 + r;
                if (outnode < NN) {
                    unsigned pk = (unsigned)__builtin_amdgcn_cvt_pk_fp8_f32(
                        acc[nt][r], acc[nt][r], 0, false);
                    h1p[(size_t)outnode * FH + nt * 16 + m] = (uchar_t)(pk & 0xffu);
                }
            }
        return;
    }

    // ================= phaseA: LDS counting sort, coalesced flush =================
    const int t = threadIdx.x;
    if (t == 0) {
        unsigned orv = 0;
        for (int i = 0; i < 16; ++i) orv |= (unsigned)edges[2 * i + 1];
        smode = (orv == 0u) ? 1 : 0;  // 1 = int64
    }
    for (int i = t; i < NB; i += 256) { hcnt[i] = 0; hcur[i] = 0; }
    __syncthreads();
    const int m = smode;
    const int base_e = blockIdx.x * ACHUNK;
    const int total = min(ACHUNK, NE - base_e);

    unsigned pay[AEPT];
    ushort_t bk[AEPT];
#pragma unroll
    for (int q = 0; q < AEPT; ++q) {
        int e = base_e + t + q * 256;
        pay[q] = 0;
        bk[q] = 0xffff;
        if (e < NE) {
            int d = load_dst(edges, m, e);
            int s = load_src(edges, m, e);
            pay[q] = ((unsigned)s << 8) | (unsigned)(d & 255);
            bk[q] = (ushort_t)(d >> 8);
            atomicAdd(&hcnt[d >> 8], 1u);
        }
    }
    __syncthreads();

    for (int i = t; i < NB; i += 256) dlt[i] = atomicAdd(&bcur[i], hcnt[i]);  // hrun
    sc[t] = (t < NB) ? hcnt[t] : 0u;
    sc[t + 256] = (t + 256 < NB) ? hcnt[t + 256] : 0u;
    __syncthreads();
    for (int ofs = 1; ofs < 512; ofs <<= 1) {
        unsigned v0 = (t >= ofs) ? sc[t - ofs] : 0u;
        unsigned v1 = (t + 256 >= ofs) ? sc[t + 256 - ofs] : 0u;
        __syncthreads();
        sc[t] += v0;
        sc[t + 256] += v1;
        __syncthreads();
    }
    for (int i = t; i < NB; i += 256) hb[i] = sc[i] - hcnt[i];
    __syncthreads();
    for (int i = t; i < NB; i += 256) dlt[i] = dlt[i] - hb[i];
    __syncthreads();

#pragma unroll
    for (int q = 0; q < AEPT; ++q) {
        if (bk[q] != 0xffff) {
            unsigned b = bk[q];
            unsigned r = atomicAdd(&hcur[b], 1u);
            unsigned idx = hb[b] + r;
            pay_lds[idx] = pay[q];
            bkt_lds[idx] = (ushort_t)b;
        }
    }
    __syncthreads();

    for (int i = t; i < total; i += 256) {
        unsigned b = bkt_lds[i];
        unsigned within = (unsigned)i + dlt[b];
        if (within < BCAP)
            staged[(size_t)b * BCAP + within] = pay_lds[i];
    }
}

// ---- phase B: bucket-base scan + per-bucket counting sort + dinv ----
__global__ __launch_bounds__(256) void k_phaseB(const unsigned* __restrict__ staged,
                                                const unsigned* __restrict__ bcur,
                                                unsigned* __restrict__ rowstart,
                                                int* __restrict__ esrc,
                                                float* __restrict__ dinv) {
    __shared__ unsigned hist[256], hb[256], hcur[256], tmp[256];
    __shared__ unsigned sbc[512];
    const int b = blockIdx.x;
    const int t = threadIdx.x;

    sbc[t] = (t < NB) ? bcur[t] : 0u;
    sbc[t + 256] = (t + 256 < NB) ? bcur[t + 256] : 0u;
    __syncthreads();
    for (int ofs = 1; ofs < 512; ofs <<= 1) {
        unsigned v0 = (t >= ofs) ? sbc[t - ofs] : 0u;
        unsigned v1 = (t + 256 >= ofs) ? sbc[t + 256 - ofs] : 0u;
        __syncthreads();
        sbc[t] += v0;
        sbc[t + 256] += v1;
        __syncthreads();
    }
    const unsigned base = (b == 0) ? 0u : sbc[b - 1];
    const unsigned cnt = min(bcur[b], (unsigned)BCAP);

    hist[t] = 0;
    hcur[t] = 0;
    __syncthreads();
    const unsigned* sb = staged + (size_t)b * BCAP;
    for (unsigned i = t; i < cnt; i += 256) atomicAdd(&hist[sb[i] & 255u], 1u);
    __syncthreads();
    unsigned x = hist[t];
    tmp[t] = x;
    __syncthreads();
    for (int ofs = 1; ofs < 256; ofs <<= 1) {
        unsigned v = (t >= ofs) ? tmp[t - ofs] : 0u;
        __syncthreads();
        tmp[t] += v;
        __syncthreads();
    }
    hb[t] = tmp[t] - x;
    int v = b * 256 + t;
    if (v <= NN) rowstart[v] = base + hb[t];
    if (v < NN) dinv[v] = rsqrtf((float)(1u + x));
    __syncthreads();
    for (unsigned i = t; i < cnt; i += 256) {
        unsigned p = sb[i];
        unsigned dlo = p & 255u;
        unsigned pos = base + hb[dlo] + atomicAdd(&hcur[dlo], 1u);
        esrc[pos] = (int)(p >> 8);
    }
}

// ---- fused layer1 aggregate + GEMM2: fp8 rows, 4 nodes/wave, 16 lanes/node ----
// epilogue stores h2p' = h2 * dinv[v]  (prescaled for gather2)
__global__ __launch_bounds__(256) void k_gather1f(const unsigned* __restrict__ rowstart,
                                                  const int* __restrict__ esrc,
                                                  const uchar_t* __restrict__ h1p,
                                                  const float* __restrict__ dinv,
                                                  const float* __restrict__ b1,
                                                  const float* __restrict__ W2,
                                                  ushort_t* __restrict__ h2p) {
    __shared__ float Ws2t[FO][FH];  // Ws2t[j][k] = W2[k][j]
    {
        int t = threadIdx.x;
#pragma unroll
        for (int i = 0; i < 4; ++i) {
            int q = t * 4 + i;
            int k = q >> 4, j = q & 15;
            Ws2t[j][k] = W2[q];
        }
    }
    __syncthreads();

    int wave = (blockIdx.x * 256 + threadIdx.x) >> 6;
    int lane = threadIdx.x & 63;
    int grp = lane >> 4;
    int fj = lane & 15;
    int v = wave * 4 + grp;
    if (v >= NN) return;

    const unsigned* h4 = (const unsigned*)h1p;  // row = 16 uints (64 fp8)
    unsigned beg = rowstart[v], end = rowstart[v + 1];
    float dv = dinv[v];
    float a0 = 0.f, a1 = 0.f, a2 = 0.f, a3 = 0.f;
    unsigned i = beg;
    int ns0 = 0, ns1 = 0, ns2 = 0, ns3 = 0;
    if (i + 3 < end) { ns0 = esrc[i]; ns1 = esrc[i + 1]; ns2 = esrc[i + 2]; ns3 = esrc[i + 3]; }
    while (i + 3 < end) {
        int s0 = ns0, s1 = ns1, s2 = ns2, s3 = ns3;
        unsigned nx = i + 4;
        if (nx + 3 < end) { ns0 = esrc[nx]; ns1 = esrc[nx + 1]; ns2 = esrc[nx + 2]; ns3 = esrc[nx + 3]; }
        float n0 = dinv[s0] * dv, n1 = dinv[s1] * dv;
        float n2 = dinv[s2] * dv, n3 = dinv[s3] * dv;
        unsigned u0 = h4[(size_t)s0 * 16 + fj];
        unsigned u1 = h4[(size_t)s1 * 16 + fj];
        unsigned u2 = h4[(size_t)s2 * 16 + fj];
        unsigned u3 = h4[(size_t)s3 * 16 + fj];
        auto l0 = __builtin_amdgcn_cvt_pk_f32_fp8(u0, false);
        auto h0 = __builtin_amdgcn_cvt_pk_f32_fp8(u0, true);
        auto l1 = __builtin_amdgcn_cvt_pk_f32_fp8(u1, false);
        auto h1 = __builtin_amdgcn_cvt_pk_f32_fp8(u1, true);
        auto l2 = __builtin_amdgcn_cvt_pk_f32_fp8(u2, false);
        auto h2 = __builtin_amdgcn_cvt_pk_f32_fp8(u2, true);
        auto l3 = __builtin_amdgcn_cvt_pk_f32_fp8(u3, false);
        auto h3 = __builtin_amdgcn_cvt_pk_f32_fp8(u3, true);
        a0 += l0[0] * n0 + l1[0] * n1 + l2[0] * n2 + l3[0] * n3;
        a1 += l0[1] * n0 + l1[1] * n1 + l2[1] * n2 + l3[1] * n3;
        a2 += h0[0] * n0 + h1[0] * n1 + h2[0] * n2 + h3[0] * n3;
        a3 += h0[1] * n0 + h1[1] * n1 + h2[1] * n2 + h3[1] * n3;
        i = nx;
    }
    for (; i < end; ++i) {
        int s = esrc[i];
        float n = dinv[s] * dv;
        unsigned u = h4[(size_t)s * 16 + fj];
        auto lo = __builtin_amdgcn_cvt_pk_f32_fp8(u, false);
        auto hi = __builtin_amdgcn_cvt_pk_f32_fp8(u, true);
        a0 += lo[0] * n;
        a1 += lo[1] * n;
        a2 += hi[0] * n;
        a3 += hi[1] * n;
    }
    float di2 = dv * dv;
    unsigned us = h4[(size_t)v * 16 + fj];
    auto slo = __builtin_amdgcn_cvt_pk_f32_fp8(us, false);
    auto shi = __builtin_amdgcn_cvt_pk_f32_fp8(us, true);
    float4 bb = ((const float4*)b1)[fj];
    float r0 = fmaxf(a0 + slo[0] * di2 + bb.x, 0.f);
    float r1 = fmaxf(a1 + slo[1] * di2 + bb.y, 0.f);
    float r2 = fmaxf(a2 + shi[0] * di2 + bb.z, 0.f);
    float r3 = fmaxf(a3 + shi[1] * di2 + bb.w, 0.f);

    float p[16];
#pragma unroll
    for (int j = 0; j < 16; ++j) {
        float4 w = *(const float4*)&Ws2t[j][fj * 4];
        p[j] = r0 * w.x + r1 * w.y + r2 * w.z + r3 * w.w;
    }
    bool c0 = (fj & 1) != 0;
    float q8[8];
#pragma unroll
    for (int k = 0; k < 8; ++k) {
        float sent = c0 ? p[2 * k] : p[2 * k + 1];
        float kept = c0 ? p[2 * k + 1] : p[2 * k];
        q8[k] = kept + __shfl_xor(sent, 1);
    }
    bool c1 = (fj & 2) != 0;
    float q4[4];
#pragma unroll
    for (int k = 0; k < 4; ++k) {
        float sent = c1 ? q8[2 * k] : q8[2 * k + 1];
        float kept = c1 ? q8[2 * k + 1] : q8[2 * k];
        q4[k] = kept + __shfl_xor(sent, 2);
    }
    bool c2 = (fj & 4) != 0;
    float q2[2];
#pragma unroll
    for (int k = 0; k < 2; ++k) {
        float sent = c2 ? q4[2 * k] : q4[2 * k + 1];
        float kept = c2 ? q4[2 * k + 1] : q4[2 * k];
        q2[k] = kept + __shfl_xor(sent, 4);
    }
    bool c3 = (fj & 8) != 0;
    {
        float sent = c3 ? q2[0] : q2[1];
        float kept = c3 ? q2[1] : q2[0];
        float fin = kept + __shfl_xor(sent, 8);
        h2p[(size_t)v * FO + fj] = f2bf(fin * dv);  // prescaled
    }
}

// ---- layer2 aggregate (rows prescaled) + bias + log_softmax ----
__global__ __launch_bounds__(256) void k_gather2(const unsigned* __restrict__ rowstart,
                                                 const int* __restrict__ esrc,
                                                 const ushort_t* __restrict__ h2p,
                                                 const float* __restrict__ dinv,
                                                 const float* __restrict__ b,
                                                 float* __restrict__ out) {
    int wave = (blockIdx.x * 256 + threadIdx.x) >> 6;
    int lane = threadIdx.x & 63;
    int grp = lane >> 4;
    int j = lane & 15;
    int v = wave * 4 + grp;
    if (v >= NN) return;
    unsigned beg = rowstart[v], end = rowstart[v + 1];
    float dv = dinv[v];
    float acc = 0.f;
    unsigned i = beg;
    int ns0 = 0, ns1 = 0, ns2 = 0, ns3 = 0;
    if (i + 3 < end) { ns0 = esrc[i]; ns1 = esrc[i + 1]; ns2 = esrc[i + 2]; ns3 = esrc[i + 3]; }
    while (i + 3 < end) {
        int s0 = ns0, s1 = ns1, s2 = ns2, s3 = ns3;
        unsigned nx = i + 4;
        if (nx + 3 < end) { ns0 = esrc[nx]; ns1 = esrc[nx + 1]; ns2 = esrc[nx + 2]; ns3 = esrc[nx + 3]; }
        float x0 = __uint_as_float((unsigned)h2p[(size_t)s0 * FO + j] << 16);
        float x1 = __uint_as_float((unsigned)h2p[(size_t)s1 * FO + j] << 16);
        float x2 = __uint_as_float((unsigned)h2p[(size_t)s2 * FO + j] << 16);
        float x3 = __uint_as_float((unsigned)h2p[(size_t)s3 * FO + j] << 16);
        acc += (x0 + x1) + (x2 + x3);
        i = nx;
    }
    for (; i < end; ++i) {
        int s = esrc[i];
        acc += __uint_as_float((unsigned)h2p[(size_t)s * FO + j] << 16);
    }
    float self = __uint_as_float((unsigned)h2p[(size_t)v * FO + j] << 16);
    float val = fmaf(acc + self, dv, b[j]);
    float m = val;
#pragma unroll
    for (int w = 1; w < 16; w <<= 1) m = fmaxf(m, __shfl_xor(m, w));
    float ex = expf(val - m);
    float ssum = ex;
#pragma unroll
    for (int w = 1; w < 16; w <<= 1) ssum += __shfl_xor(ssum, w);
    float res = val - (m + logf(ssum));
    out[(size_t)v * FO + j] = res;
}

extern "C" void kernel_launch(void* const* d_in, const int* in_sizes, int n_in,
                              void* d_out, int out_size, void* d_ws, size_t ws_size,
                              hipStream_t stream) {
    const float* x = (const float*)d_in[0];
    const int* edges = (const int*)d_in[1];
    const float* W1 = (const float*)d_in[2];
    const float* b1 = (const float*)d_in[3];
    const float* W2 = (const float*)d_in[4];
    const float* b2 = (const float*)d_in[5];
    float* out = (float*)d_out;

    char* ws = (char*)d_ws;
    size_t off = 0;
    auto take = [&](size_t bytes) {
        void* p = ws + off;
        off += (bytes + 255) & ~(size_t)255;
        return p;
    };
    unsigned* bcur = (unsigned*)take((size_t)NB * 4);
    unsigned* rowstart = (unsigned*)take((size_t)(NN + 1) * 4);
    float* dinv = (float*)take((size_t)NN * 4);
    int* esrc = (int*)take((size_t)NE * 4);
    uchar_t* h1p = (uchar_t*)take((size_t)NN * FH);         // fp8 e4m3
    ushort_t* h2p = (ushort_t*)take((size_t)NN * FO * 2);   // bf16, prescaled
    unsigned* staged = (unsigned*)take((size_t)NB * BCAP * 4);  // 8.8 MB

    hipMemsetAsync(bcur, 0, (size_t)NB * 4, stream);
    k_fuseA<<<ABLK + GBLK, 256, 0, stream>>>(edges, bcur, staged, x, W1, h1p);
    k_phaseB<<<NB, 256, 0, stream>>>(staged, bcur, rowstart, esrc, dinv);
    k_gather1f<<<(NN + 15) / 16, 256, 0, stream>>>(rowstart, esrc, h1p, dinv, b1, W2, h2p);
    k_gather2<<<(NN + 15) / 16, 256, 0, stream>>>(rowstart, esrc, h2p, dinv, b2, out);
}

// Round 16
// 104.320 us; speedup vs baseline: 1.1411x; 1.0030x over previous
//
#include <hip/hip_runtime.h>
#include <math.h>

#define NN 100000
#define NE 1600000
#define FI 128
#define FH 64
#define FO 16
#define NB 392            // buckets of 256 nodes
#define BCAP 5632
#define AEPT 32
#define ACHUNK (256 * AEPT)                 // 8192 edges per phase-A block
#define ABLK ((NE + ACHUNK - 1) / ACHUNK)   // 196
#define GBLK ((NN + 63) / 64)               // 1563 gemm1 blocks

typedef unsigned short ushort_t;
typedef unsigned char uchar_t;
typedef __attribute__((ext_vector_type(8))) short bf16x8;
typedef __attribute__((ext_vector_type(4))) float f32x4;

__device__ __forceinline__ ushort_t f2bf(float f) {
    unsigned u = __float_as_uint(f);
    u = (u + 0x7fffu + ((u >> 16) & 1u)) >> 16;  // RNE
    return (ushort_t)u;
}

__device__ __forceinline__ int load_dst(const int* edges, int mode, int e) {
    return mode ? edges[2 * (NE + e)] : edges[NE + e];
}
__device__ __forceinline__ int load_src(const int* edges, int mode, int e) {
    return mode ? edges[2 * e] : edges[e];
}

// ---- fused: blocks [0,ABLK) = phaseA edge sort; blocks [ABLK,..) = gemm1 MFMA ----
__global__ __launch_bounds__(256) void k_fuseA(const int* __restrict__ edges,
                                               unsigned* __restrict__ bcur,
                                               unsigned* __restrict__ staged,
                                               const float* __restrict__ x,
                                               const float* __restrict__ W1,
                                               uchar_t* __restrict__ h1p) {
    __shared__ unsigned pay_lds[ACHUNK];       // 32 KB
    __shared__ ushort_t bkt_lds[ACHUNK];       // 16 KB
    __shared__ unsigned hcnt[NB], hb[NB], dlt[NB], hcur[NB];  // 6.1 KB
    __shared__ unsigned sc[512];
    __shared__ int smode;

    if (blockIdx.x >= ABLK) {
        // ================= gemm1: MFMA bf16 16x16x32, fp8 output =================
        const int tid = threadIdx.x;
        const int l = tid & 63;
        const int w = tid >> 6;
        const int m = l & 15;
        const int g = l >> 4;
        const int node0 = (blockIdx.x - ABLK) * 64 + w * 16;

        bf16x8 bfrag[4][4];
#pragma unroll
        for (int ks = 0; ks < 4; ++ks)
#pragma unroll
            for (int nt = 0; nt < 4; ++nt)
#pragma unroll
                for (int e = 0; e < 8; ++e)
                    bfrag[ks][nt][e] = (short)f2bf(W1[(ks * 32 + g * 8 + e) * FH + nt * 16 + m]);

        f32x4 acc[4];
#pragma unroll
        for (int nt = 0; nt < 4; ++nt) acc[nt] = (f32x4){0.f, 0.f, 0.f, 0.f};

        int node = node0 + m;
        const float* xrow = x + (size_t)(node < NN ? node : NN - 1) * FI;
#pragma unroll
        for (int ks = 0; ks < 4; ++ks) {
            float4 xa = *(const float4*)&xrow[ks * 32 + g * 8];
            float4 xb = *(const float4*)&xrow[ks * 32 + g * 8 + 4];
            bf16x8 afrag;
            afrag[0] = (short)f2bf(xa.x);
            afrag[1] = (short)f2bf(xa.y);
            afrag[2] = (short)f2bf(xa.z);
            afrag[3] = (short)f2bf(xa.w);
            afrag[4] = (short)f2bf(xb.x);
            afrag[5] = (short)f2bf(xb.y);
            afrag[6] = (short)f2bf(xb.z);
            afrag[7] = (short)f2bf(xb.w);
#pragma unroll
            for (int nt = 0; nt < 4; ++nt)
                acc[nt] = __builtin_amdgcn_mfma_f32_16x16x32_bf16(afrag, bfrag[ks][nt], acc[nt], 0, 0, 0);
        }
#pragma unroll
        for (int nt = 0; nt < 4; ++nt)
#pragma unroll
            for (int r = 0; r < 4; ++r) {
                int outnode = node0 + g * 4 + r;
                if (outnode < NN) {
                    unsigned pk = (unsigned)__builtin_amdgcn_cvt_pk_fp8_f32(
                        acc[nt][r], acc[nt][r], 0, false);
                    h1p[(size_t)outnode * FH + nt * 16 + m] = (uchar_t)(pk & 0xffu);
                }
            }
        return;
    }

    // ================= phaseA: LDS counting sort, coalesced flush =================
    const int t = threadIdx.x;
    if (t == 0) {
        unsigned orv = 0;
        for (int i = 0; i < 16; ++i) orv |= (unsigned)edges[2 * i + 1];
        smode = (orv == 0u) ? 1 : 0;  // 1 = int64
    }
    for (int i = t; i < NB; i += 256) { hcnt[i] = 0; hcur[i] = 0; }
    __syncthreads();
    const int m = smode;
    const int base_e = blockIdx.x * ACHUNK;
    const int total = min(ACHUNK, NE - base_e);

    unsigned pay[AEPT];
    ushort_t bk[AEPT];
#pragma unroll
    for (int q = 0; q < AEPT; ++q) {
        int e = base_e + t + q * 256;
        pay[q] = 0;
        bk[q] = 0xffff;
        if (e < NE) {
            int d = load_dst(edges, m, e);
            int s = load_src(edges, m, e);
            pay[q] = ((unsigned)s << 8) | (unsigned)(d & 255);
            bk[q] = (ushort_t)(d >> 8);
            atomicAdd(&hcnt[d >> 8], 1u);
        }
    }
    __syncthreads();

    for (int i = t; i < NB; i += 256) dlt[i] = atomicAdd(&bcur[i], hcnt[i]);  // hrun
    sc[t] = (t < NB) ? hcnt[t] : 0u;
    sc[t + 256] = (t + 256 < NB) ? hcnt[t + 256] : 0u;
    __syncthreads();
    for (int ofs = 1; ofs < 512; ofs <<= 1) {
        unsigned v0 = (t >= ofs) ? sc[t - ofs] : 0u;
        unsigned v1 = (t + 256 >= ofs) ? sc[t + 256 - ofs] : 0u;
        __syncthreads();
        sc[t] += v0;
        sc[t + 256] += v1;
        __syncthreads();
    }
    for (int i = t; i < NB; i += 256) hb[i] = sc[i] - hcnt[i];
    __syncthreads();
    for (int i = t; i < NB; i += 256) dlt[i] = dlt[i] - hb[i];
    __syncthreads();

#pragma unroll
    for (int q = 0; q < AEPT; ++q) {
        if (bk[q] != 0xffff) {
            unsigned b = bk[q];
            unsigned r = atomicAdd(&hcur[b], 1u);
            unsigned idx = hb[b] + r;
            pay_lds[idx] = pay[q];
            bkt_lds[idx] = (ushort_t)b;
        }
    }
    __syncthreads();

    for (int i = t; i < total; i += 256) {
        unsigned b = bkt_lds[i];
        unsigned within = (unsigned)i + dlt[b];
        if (within < BCAP)
            staged[(size_t)b * BCAP + within] = pay_lds[i];
    }
}

// ---- phase B: bucket-base scan + per-bucket counting sort + dinv ----
__global__ __launch_bounds__(256) void k_phaseB(const unsigned* __restrict__ staged,
                                                const unsigned* __restrict__ bcur,
                                                unsigned* __restrict__ rowstart,
                                                int* __restrict__ esrc,
                                                float* __restrict__ dinv) {
    __shared__ unsigned hist[256], hb[256], hcur[256], tmp[256];
    __shared__ unsigned sbc[512];
    const int b = blockIdx.x;
    const int t = threadIdx.x;

    sbc[t] = (t < NB) ? bcur[t] : 0u;
    sbc[t + 256] = (t + 256 < NB) ? bcur[t + 256] : 0u;
    __syncthreads();
    for (int ofs = 1; ofs < 512; ofs <<= 1) {
        unsigned v0 = (t >= ofs) ? sbc[t - ofs] : 0u;
        unsigned v1 = (t + 256 >= ofs) ? sbc[t + 256 - ofs] : 0u;
        __syncthreads();
        sbc[t] += v0;
        sbc[t + 256] += v1;
        __syncthreads();
    }
    const unsigned base = (b == 0) ? 0u : sbc[b - 1];
    const unsigned cnt = min(bcur[b], (unsigned)BCAP);

    hist[t] = 0;
    hcur[t] = 0;
    __syncthreads();
    const unsigned* sb = staged + (size_t)b * BCAP;
    for (unsigned i = t; i < cnt; i += 256) atomicAdd(&hist[sb[i] & 255u], 1u);
    __syncthreads();
    unsigned x = hist[t];
    tmp[t] = x;
    __syncthreads();
    for (int ofs = 1; ofs < 256; ofs <<= 1) {
        unsigned v = (t >= ofs) ? tmp[t - ofs] : 0u;
        __syncthreads();
        tmp[t] += v;
        __syncthreads();
    }
    hb[t] = tmp[t] - x;
    int v = b * 256 + t;
    if (v <= NN) rowstart[v] = base + hb[t];
    if (v < NN) dinv[v] = rsqrtf((float)(1u + x));
    __syncthreads();
    for (unsigned i = t; i < cnt; i += 256) {
        unsigned p = sb[i];
        unsigned dlo = p & 255u;
        unsigned pos = base + hb[dlo] + atomicAdd(&hcur[dlo], 1u);
        esrc[pos] = (int)(p >> 8);
    }
}

// ---- fused layer1 aggregate + GEMM2: fp8 rows, 4 nodes/wave, 16 lanes/node, MLP 8 ----
// epilogue stores h2p' = h2 * dinv[v]  (prescaled for gather2)
__global__ __launch_bounds__(256) void k_gather1f(const unsigned* __restrict__ rowstart,
                                                  const int* __restrict__ esrc,
                                                  const uchar_t* __restrict__ h1p,
                                                  const float* __restrict__ dinv,
                                                  const float* __restrict__ b1,
                                                  const float* __restrict__ W2,
                                                  ushort_t* __restrict__ h2p) {
    __shared__ float Ws2t[FO][FH];  // Ws2t[j][k] = W2[k][j]
    {
        int t = threadIdx.x;
#pragma unroll
        for (int i = 0; i < 4; ++i) {
            int q = t * 4 + i;
            int k = q >> 4, j = q & 15;
            Ws2t[j][k] = W2[q];
        }
    }
    __syncthreads();

    int wave = (blockIdx.x * 256 + threadIdx.x) >> 6;
    int lane = threadIdx.x & 63;
    int grp = lane >> 4;
    int fj = lane & 15;
    int v = wave * 4 + grp;
    if (v >= NN) return;

    const unsigned* h4 = (const unsigned*)h1p;  // row = 16 uints (64 fp8)
    unsigned beg = rowstart[v], end = rowstart[v + 1];
    float dv = dinv[v];
    float a0 = 0.f, a1 = 0.f, a2 = 0.f, a3 = 0.f;
    unsigned i = beg;

#define EDGE1(sv, nv)                                              \
    {                                                              \
        unsigned u = h4[(size_t)(sv)*16 + fj];                     \
        auto lo = __builtin_amdgcn_cvt_pk_f32_fp8(u, false);       \
        auto hi = __builtin_amdgcn_cvt_pk_f32_fp8(u, true);        \
        a0 += lo[0] * (nv);                                        \
        a1 += lo[1] * (nv);                                        \
        a2 += hi[0] * (nv);                                        \
        a3 += hi[1] * (nv);                                        \
    }

    for (; i + 7 < end; i += 8) {
        int s0 = esrc[i], s1 = esrc[i + 1], s2 = esrc[i + 2], s3 = esrc[i + 3];
        int s4 = esrc[i + 4], s5 = esrc[i + 5], s6 = esrc[i + 6], s7 = esrc[i + 7];
        float n0 = dinv[s0] * dv, n1 = dinv[s1] * dv, n2 = dinv[s2] * dv, n3 = dinv[s3] * dv;
        float n4 = dinv[s4] * dv, n5 = dinv[s5] * dv, n6 = dinv[s6] * dv, n7 = dinv[s7] * dv;
        EDGE1(s0, n0);
        EDGE1(s1, n1);
        EDGE1(s2, n2);
        EDGE1(s3, n3);
        EDGE1(s4, n4);
        EDGE1(s5, n5);
        EDGE1(s6, n6);
        EDGE1(s7, n7);
    }
    for (; i + 3 < end; i += 4) {
        int s0 = esrc[i], s1 = esrc[i + 1], s2 = esrc[i + 2], s3 = esrc[i + 3];
        float n0 = dinv[s0] * dv, n1 = dinv[s1] * dv, n2 = dinv[s2] * dv, n3 = dinv[s3] * dv;
        EDGE1(s0, n0);
        EDGE1(s1, n1);
        EDGE1(s2, n2);
        EDGE1(s3, n3);
    }
    for (; i < end; ++i) {
        int s = esrc[i];
        float n = dinv[s] * dv;
        EDGE1(s, n);
    }
#undef EDGE1

    float di2 = dv * dv;
    unsigned us = h4[(size_t)v * 16 + fj];
    auto slo = __builtin_amdgcn_cvt_pk_f32_fp8(us, false);
    auto shi = __builtin_amdgcn_cvt_pk_f32_fp8(us, true);
    float4 bb = ((const float4*)b1)[fj];
    float r0 = fmaxf(a0 + slo[0] * di2 + bb.x, 0.f);
    float r1 = fmaxf(a1 + slo[1] * di2 + bb.y, 0.f);
    float r2 = fmaxf(a2 + shi[0] * di2 + bb.z, 0.f);
    float r3 = fmaxf(a3 + shi[1] * di2 + bb.w, 0.f);

    float p[16];
#pragma unroll
    for (int j = 0; j < 16; ++j) {
        float4 w = *(const float4*)&Ws2t[j][fj * 4];
        p[j] = r0 * w.x + r1 * w.y + r2 * w.z + r3 * w.w;
    }
    bool c0 = (fj & 1) != 0;
    float q8[8];
#pragma unroll
    for (int k = 0; k < 8; ++k) {
        float sent = c0 ? p[2 * k] : p[2 * k + 1];
        float kept = c0 ? p[2 * k + 1] : p[2 * k];
        q8[k] = kept + __shfl_xor(sent, 1);
    }
    bool c1 = (fj & 2) != 0;
    float q4[4];
#pragma unroll
    for (int k = 0; k < 4; ++k) {
        float sent = c1 ? q8[2 * k] : q8[2 * k + 1];
        float kept = c1 ? q8[2 * k + 1] : q8[2 * k];
        q4[k] = kept + __shfl_xor(sent, 2);
    }
    bool c2 = (fj & 4) != 0;
    float q2[2];
#pragma unroll
    for (int k = 0; k < 2; ++k) {
        float sent = c2 ? q4[2 * k] : q4[2 * k + 1];
        float kept = c2 ? q4[2 * k + 1] : q4[2 * k];
        q2[k] = kept + __shfl_xor(sent, 4);
    }
    bool c3 = (fj & 8) != 0;
    {
        float sent = c3 ? q2[0] : q2[1];
        float kept = c3 ? q2[1] : q2[0];
        float fin = kept + __shfl_xor(sent, 8);
        h2p[(size_t)v * FO + fj] = f2bf(fin * dv);  // prescaled
    }
}

// ---- layer2 aggregate (rows prescaled) + bias + log_softmax ----
__global__ __launch_bounds__(256) void k_gather2(const unsigned* __restrict__ rowstart,
                                                 const int* __restrict__ esrc,
                                                 const ushort_t* __restrict__ h2p,
                                                 const float* __restrict__ dinv,
                                                 const float* __restrict__ b,
                                                 float* __restrict__ out) {
    int wave = (blockIdx.x * 256 + threadIdx.x) >> 6;
    int lane = threadIdx.x & 63;
    int grp = lane >> 4;
    int j = lane & 15;
    int v = wave * 4 + grp;
    if (v >= NN) return;
    unsigned beg = rowstart[v], end = rowstart[v + 1];
    float dv = dinv[v];
    float acc = 0.f;
    unsigned i = beg;
    for (; i + 7 < end; i += 8) {
        int s0 = esrc[i], s1 = esrc[i + 1], s2 = esrc[i + 2], s3 = esrc[i + 3];
        int s4 = esrc[i + 4], s5 = esrc[i + 5], s6 = esrc[i + 6], s7 = esrc[i + 7];
        float x0 = __uint_as_float((unsigned)h2p[(size_t)s0 * FO + j] << 16);
        float x1 = __uint_as_float((unsigned)h2p[(size_t)s1 * FO + j] << 16);
        float x2 = __uint_as_float((unsigned)h2p[(size_t)s2 * FO + j] << 16);
        float x3 = __uint_as_float((unsigned)h2p[(size_t)s3 * FO + j] << 16);
        float x4 = __uint_as_float((unsigned)h2p[(size_t)s4 * FO + j] << 16);
        float x5 = __uint_as_float((unsigned)h2p[(size_t)s5 * FO + j] << 16);
        float x6 = __uint_as_float((unsigned)h2p[(size_t)s6 * FO + j] << 16);
        float x7 = __uint_as_float((unsigned)h2p[(size_t)s7 * FO + j] << 16);
        acc += ((x0 + x1) + (x2 + x3)) + ((x4 + x5) + (x6 + x7));
    }
    for (; i + 3 < end; i += 4) {
        int s0 = esrc[i], s1 = esrc[i + 1], s2 = esrc[i + 2], s3 = esrc[i + 3];
        float x0 = __uint_as_float((unsigned)h2p[(size_t)s0 * FO + j] << 16);
        float x1 = __uint_as_float((unsigned)h2p[(size_t)s1 * FO + j] << 16);
        float x2 = __uint_as_float((unsigned)h2p[(size_t)s2 * FO + j] << 16);
        float x3 = __uint_as_float((unsigned)h2p[(size_t)s3 * FO + j] << 16);
        acc += (x0 + x1) + (x2 + x3);
    }
    for (; i < end; ++i) {
        int s = esrc[i];
        acc += __uint_as_float((unsigned)h2p[(size_t)s * FO + j] << 16);
    }
    float self = __uint_as_float((unsigned)h2p[(size_t)v * FO + j] << 16);
    float val = fmaf(acc + self, dv, b[j]);
    float m = val;
#pragma unroll
    for (int w = 1; w < 16; w <<= 1) m = fmaxf(m, __shfl_xor(m, w));
    float ex = expf(val - m);
    float ssum = ex;
#pragma unroll
    for (int w = 1; w < 16; w <<= 1) ssum += __shfl_xor(ssum, w);
    float res = val - (m + logf(ssum));
    out[(size_t)v * FO + j] = res;
}

extern "C" void kernel_launch(void* const* d_in, const int* in_sizes, int n_in,
                              void* d_out, int out_size, void* d_ws, size_t ws_size,
                              hipStream_t stream) {
    const float* x = (const float*)d_in[0];
    const int* edges = (const int*)d_in[1];
    const float* W1 = (const float*)d_in[2];
    const float* b1 = (const float*)d_in[3];
    const float* W2 = (const float*)d_in[4];
    const float* b2 = (const float*)d_in[5];
    float* out = (float*)d_out;

    char* ws = (char*)d_ws;
    size_t off = 0;
    auto take = [&](size_t bytes) {
        void* p = ws + off;
        off += (bytes + 255) & ~(size_t)255;
        return p;
    };
    unsigned* bcur = (unsigned*)take((size_t)NB * 4);
    unsigned* rowstart = (unsigned*)take((size_t)(NN + 1) * 4);
    float* dinv = (float*)take((size_t)NN * 4);
    int* esrc = (int*)take((size_t)NE * 4);
    uchar_t* h1p = (uchar_t*)take((size_t)NN * FH);         // fp8 e4m3
    ushort_t* h2p = (ushort_t*)take((size_t)NN * FO * 2);   // bf16, prescaled
    unsigned* staged = (unsigned*)take((size_t)NB * BCAP * 4);  // 8.8 MB

    hipMemsetAsync(bcur, 0, (size_t)NB * 4, stream);
    k_fuseA<<<ABLK + GBLK, 256, 0, stream>>>(edges, bcur, staged, x, W1, h1p);
    k_phaseB<<<NB, 256, 0, stream>>>(staged, bcur, rowstart, esrc, dinv);
    k_gather1f<<<(NN + 15) / 16, 256, 0, stream>>>(rowstart, esrc, h1p, dinv, b1, W2, h2p);
    k_gather2<<<(NN + 15) / 16, 256, 0, stream>>>(rowstart, esrc, h2p, dinv, b2, out);
}